// Round 10
// baseline (1201.579 us; speedup 1.0000x reference)
//
#include <hip/hip_runtime.h>

// LSTMPredictor: 2-layer LSTMCell (H=51), L=1000 steps + 100 autoregressive,
// B=256 chains. One block/batch element (grid=256=#CUs), 768 threads.
//
// R10: SINGLE-BARRIER STEP via redundant lane-local state.
//  - Every wave keeps h-state in registers: lane l of G0/G1 waves holds
//    h1[l],c1[l]; lane l of G2 waves holds h2[l],c2[l]. The update is done
//    REDUNDANTLY by every wave (identical FP ops -> identical values), so
//    there is no dedicated update phase and no idle waves.
//  - Matvec h-broadcast = v_readlane from the wave's OWN lane-local h
//    (no LDS for h at all).
//  - Only gates cross waves: double-buffered gbuf[2][3][256], unit-major
//    (unit u's 4 gates contiguous -> one ds_read_b128 per lane), with the
//    row remap r=(j&3)*51+(j>>2) making gate writes contiguous b32.
//  - Hot loop (t<1000): ONE barrier/step. Future loop: +1 mid-barrier for
//    the out_s autoregressive feedback.
// Groups: G0 (tid 0..255): W_hh1 rows -> g1p(t+1); G1 (256..511): W_ih2 ->
// gA(t); G2 (512..767): W_hh2 -> gB(t). act = (tid&255) < 204.
// Weights register-resident: named scalars + asm pin + waves_per_eu(3,3).

#define B_   256
#define L_   1000
#define H_   51
#define T_   1100

__device__ __forceinline__ float frcp(float v) { return __builtin_amdgcn_rcpf(v); }
__device__ __forceinline__ float sigf(float v) {
    return frcp(1.0f + __expf(-v));
}
__device__ __forceinline__ float tanh_fast(float v) {
    float a = fminf(fmaxf(v, -9.0f), 9.0f);
    float e = __expf(2.0f * a);
    return (e - 1.0f) * frcp(e + 1.0f);
}

// one broadcast-FMA term: h[k] via readlane of lane-local h, weight in VGPR
#define RLF(k, acc) acc = fmaf(__int_as_float(__builtin_amdgcn_readlane(vhi, k)), wr##k, acc)

#define MATVEC(dst) do { \
    const int vhi = __float_as_int(hl); \
    float a0 = bias, a1 = 0.f, a2 = 0.f, a3 = 0.f; \
    RLF(0,a0);  RLF(1,a1);  RLF(2,a2);  RLF(3,a3); \
    RLF(4,a0);  RLF(5,a1);  RLF(6,a2);  RLF(7,a3); \
    RLF(8,a0);  RLF(9,a1);  RLF(10,a2); RLF(11,a3); \
    RLF(12,a0); RLF(13,a1); RLF(14,a2); RLF(15,a3); \
    RLF(16,a0); RLF(17,a1); RLF(18,a2); RLF(19,a3); \
    RLF(20,a0); RLF(21,a1); RLF(22,a2); RLF(23,a3); \
    RLF(24,a0); RLF(25,a1); RLF(26,a2); RLF(27,a3); \
    RLF(28,a0); RLF(29,a1); RLF(30,a2); RLF(31,a3); \
    RLF(32,a0); RLF(33,a1); RLF(34,a2); RLF(35,a3); \
    RLF(36,a0); RLF(37,a1); RLF(38,a2); RLF(39,a3); \
    RLF(40,a0); RLF(41,a1); RLF(42,a2); RLF(43,a3); \
    RLF(44,a0); RLF(45,a1); RLF(46,a2); RLF(47,a3); \
    RLF(48,a0); RLF(49,a1); RLF(50,a2); \
    (dst) = (a0 + a1) + (a2 + a3); } while (0)

__attribute__((amdgpu_flat_work_group_size(768, 768), amdgpu_waves_per_eu(3, 3)))
__global__ void lstm_pred_kernel(const float* __restrict__ x,
                      const float* __restrict__ W_ih1, const float* __restrict__ W_hh1,
                      const float* __restrict__ b_ih1, const float* __restrict__ b_hh1,
                      const float* __restrict__ W_ih2, const float* __restrict__ W_hh2,
                      const float* __restrict__ b_ih2, const float* __restrict__ b_hh2,
                      const float* __restrict__ W_lin, const float* __restrict__ b_lin,
                      float* __restrict__ out)
{
    __shared__ float xrow[L_];
    __shared__ alignas(16) float gbuf[2][3][256];  // [buf][mat][unit*4+gate]
    __shared__ float out_s;

    const int tid  = threadIdx.x;
    const int b    = blockIdx.x;
    const int lane = tid & 63;
    const int wv   = tid >> 6;      // wave 0..11
    const int grp  = tid >> 8;      // 0,1,2
    const int j    = tid & 255;
    const bool act = (j < 204);

    for (int i = tid; i < L_; i += 768) xrow[i] = x[(size_t)b * L_ + i];

    // ---- matvec row mapping: r = (gate)*51 + (unit), j = unit*4 + gate ----
    const int r = (j & 3) * H_ + (j >> 2);
    const float* Wsrc = (grp == 0) ? W_hh1 : (grp == 1) ? W_ih2 : W_hh2;
    const float* wrow = Wsrc + r * H_;
    float bias = 0.0f;
    float wr0=0.f,wr1=0.f,wr2=0.f,wr3=0.f,wr4=0.f,wr5=0.f,wr6=0.f,wr7=0.f,
          wr8=0.f,wr9=0.f,wr10=0.f,wr11=0.f,wr12=0.f,wr13=0.f,wr14=0.f,wr15=0.f,
          wr16=0.f,wr17=0.f,wr18=0.f,wr19=0.f,wr20=0.f,wr21=0.f,wr22=0.f,wr23=0.f,
          wr24=0.f,wr25=0.f,wr26=0.f,wr27=0.f,wr28=0.f,wr29=0.f,wr30=0.f,wr31=0.f,
          wr32=0.f,wr33=0.f,wr34=0.f,wr35=0.f,wr36=0.f,wr37=0.f,wr38=0.f,wr39=0.f,
          wr40=0.f,wr41=0.f,wr42=0.f,wr43=0.f,wr44=0.f,wr45=0.f,wr46=0.f,wr47=0.f,
          wr48=0.f,wr49=0.f,wr50=0.f;
    if (act) {
        if (grp == 0)      bias = b_ih1[r] + b_hh1[r];
        else if (grp == 1) bias = b_ih2[r] + b_hh2[r];
        wr0 =wrow[0];  wr1 =wrow[1];  wr2 =wrow[2];  wr3 =wrow[3];
        wr4 =wrow[4];  wr5 =wrow[5];  wr6 =wrow[6];  wr7 =wrow[7];
        wr8 =wrow[8];  wr9 =wrow[9];  wr10=wrow[10]; wr11=wrow[11];
        wr12=wrow[12]; wr13=wrow[13]; wr14=wrow[14]; wr15=wrow[15];
        wr16=wrow[16]; wr17=wrow[17]; wr18=wrow[18]; wr19=wrow[19];
        wr20=wrow[20]; wr21=wrow[21]; wr22=wrow[22]; wr23=wrow[23];
        wr24=wrow[24]; wr25=wrow[25]; wr26=wrow[26]; wr27=wrow[27];
        wr28=wrow[28]; wr29=wrow[29]; wr30=wrow[30]; wr31=wrow[31];
        wr32=wrow[32]; wr33=wrow[33]; wr34=wrow[34]; wr35=wrow[35];
        wr36=wrow[36]; wr37=wrow[37]; wr38=wrow[38]; wr39=wrow[39];
        wr40=wrow[40]; wr41=wrow[41]; wr42=wrow[42]; wr43=wrow[43];
        wr44=wrow[44]; wr45=wrow[45]; wr46=wrow[46]; wr47=wrow[47];
        wr48=wrow[48]; wr49=wrow[49]; wr50=wrow[50];
    }
    asm volatile("" :
        "+v"(wr0),"+v"(wr1),"+v"(wr2),"+v"(wr3),"+v"(wr4),"+v"(wr5),"+v"(wr6),
        "+v"(wr7),"+v"(wr8),"+v"(wr9),"+v"(wr10),"+v"(wr11),"+v"(wr12),"+v"(wr13),
        "+v"(wr14),"+v"(wr15),"+v"(wr16),"+v"(wr17),"+v"(wr18),"+v"(wr19),
        "+v"(wr20),"+v"(wr21),"+v"(wr22),"+v"(wr23),"+v"(wr24),"+v"(wr25));
    asm volatile("" :
        "+v"(wr26),"+v"(wr27),"+v"(wr28),"+v"(wr29),"+v"(wr30),"+v"(wr31),
        "+v"(wr32),"+v"(wr33),"+v"(wr34),"+v"(wr35),"+v"(wr36),"+v"(wr37),
        "+v"(wr38),"+v"(wr39),"+v"(wr40),"+v"(wr41),"+v"(wr42),"+v"(wr43),
        "+v"(wr44),"+v"(wr45),"+v"(wr46),"+v"(wr47),"+v"(wr48),"+v"(wr49),
        "+v"(wr50),"+v"(bias));

    // ---- update-role registers (per-lane unit = lane) ----
    float wiu0=0.f, wiu1=0.f, wiu2=0.f, wiu3=0.f, wl=0.f;
    if (grp < 2) {
        if (lane < H_) {
            wiu0 = W_ih1[lane];
            wiu1 = W_ih1[lane + H_];
            wiu2 = W_ih1[lane + 2 * H_];
            wiu3 = W_ih1[lane + 3 * H_];
        }
    } else {
        if (lane < H_) wl = W_lin[lane];
    }
    const float blin = b_lin[0];
    float hl = 0.0f, cl = 0.0f;   // lane-local state: h1/c1 (G0,G1) or h2/c2 (G2)
    float* outp = out + (size_t)b * T_;

    // ---- prologue: g1p(0) = bias1 (h1(-1)=0) ----
    if (grp == 0 && act) gbuf[0][0][j] = bias;
    __syncthreads();

    int p = 0;
    for (int t = 0; t <= T_; ++t) {
        const bool fut = (t >= L_);

        // G2: update h2(t-1) from gA(t-1)+gB(t-1); emit out(t-1)
        if (grp == 2 && t > 0) {
            const float4 ga = *(const float4*)&gbuf[p][1][4 * lane];
            const float4 gb = *(const float4*)&gbuf[p][2][4 * lane];
            float ig = sigf(ga.x + gb.x);
            float fg = sigf(ga.y + gb.y);
            float gv = tanh_fast(ga.z + gb.z);
            float og = sigf(ga.w + gb.w);
            cl = fmaf(fg, cl, ig * gv);
            hl = og * tanh_fast(cl);
            if (wv == 8) {
                float pp = (lane < H_) ? hl * wl : 0.0f;
#pragma unroll
                for (int off = 32; off > 0; off >>= 1) pp += __shfl_down(pp, off);
                if (lane == 0) {
                    float o = pp + blin;
                    outp[t - 1] = o;
                    if (fut) out_s = o;
                }
            }
        }

        if (fut) __syncthreads();   // out_s feedback visibility (101 iters only)

        // G0/G1: update h1(t) from g1p(t) + x(t)*W_ih1 (redundant in 8 waves)
        if (grp < 2 && t < T_) {
            const float4 g1 = *(const float4*)&gbuf[p][0][4 * lane];
            const float xv = fut ? out_s : xrow[t];
            float ig = sigf(fmaf(wiu0, xv, g1.x));
            float fg = sigf(fmaf(wiu1, xv, g1.y));
            float gv = tanh_fast(fmaf(wiu2, xv, g1.z));
            float og = sigf(fmaf(wiu3, xv, g1.w));
            cl = fmaf(fg, cl, ig * gv);
            hl = og * tanh_fast(cl);
        }

        // All groups: matvec from lane-local h, write gates(t'') to buf p^1
        if (t < T_ && act) {
            MATVEC(gbuf[p ^ 1][grp][j]);
        }
        __syncthreads();
        p ^= 1;
    }
}

extern "C" void kernel_launch(void* const* d_in, const int* in_sizes, int n_in,
                              void* d_out, int out_size, void* d_ws, size_t ws_size,
                              hipStream_t stream)
{
    const float* x     = (const float*)d_in[0];
    const float* W_ih1 = (const float*)d_in[1];
    const float* W_hh1 = (const float*)d_in[2];
    const float* b_ih1 = (const float*)d_in[3];
    const float* b_hh1 = (const float*)d_in[4];
    const float* W_ih2 = (const float*)d_in[5];
    const float* W_hh2 = (const float*)d_in[6];
    const float* b_ih2 = (const float*)d_in[7];
    const float* b_hh2 = (const float*)d_in[8];
    const float* W_lin = (const float*)d_in[9];
    const float* b_lin = (const float*)d_in[10];
    float* out = (float*)d_out;

    lstm_pred_kernel<<<B_, 768, 0, stream>>>(x, W_ih1, W_hh1, b_ih1, b_hh1,
                                             W_ih2, W_hh2, b_ih2, b_hh2,
                                             W_lin, b_lin, out);
}